// Round 4
// baseline (312.751 us; speedup 1.0000x reference)
//
#include <hip/hip_runtime.h>

// img: [B=256, C=3, H=224, W=224] fp32; y_idx/x_idx: [B] int32; 32x32 square
// zeroed per batch across channels. Single fused streaming kernel.
//
// W=224 = 14 chunks of 16 floats (64B). Each thread owns one contiguous 64B
// chunk => chunk never crosses a row => ONE index-decode per 64B.
// Grid exact: 2,408,448 chunks = 9408 blocks x 256 threads, no bounds check.
// Nontemporal ld/st (native clang vector type — HIP float4 is a struct and
// is rejected by the builtin).

#define SQ 32
#define B_ 256
#define C_ 3
#define H_ 224
#define W_ 224

typedef float vf4 __attribute__((ext_vector_type(4)));

__global__ __launch_bounds__(256) void rsd_kernel(const vf4* __restrict__ src,
                                                  const int* __restrict__ y_idx,
                                                  const int* __restrict__ x_idx,
                                                  vf4* __restrict__ dst) {
    int i16 = blockIdx.x * 256 + threadIdx.x;   // chunk index (16 floats / 64B)

    // Decode: row t = i16/14, w0 = (i16%14)*16; h = t%224; b = (t/224)/3
    int t  = i16 / 14;
    int w0 = (i16 - t * 14) << 4;
    int bc = t / H_;
    int h  = t - bc * H_;
    int b  = bc / C_;   // bc = b*3 + c; c irrelevant (same square all channels)

    int i4 = i16 << 2;  // first float4 of this chunk
    vf4 v0 = __builtin_nontemporal_load(src + i4 + 0);
    vf4 v1 = __builtin_nontemporal_load(src + i4 + 1);
    vf4 v2 = __builtin_nontemporal_load(src + i4 + 2);
    vf4 v3 = __builtin_nontemporal_load(src + i4 + 3);

    int y0 = y_idx[b];
    int x0 = x_idx[b];

    if (h >= y0 && h < y0 + SQ) {
        // overlap of [w0, w0+16) with [x0, x0+32), chunk-local coords
        int lo = x0 - w0;            // first zeroed element (may be <0)
        int hi = lo + SQ;            // one past last
        if (lo < 16 && hi > 0) {
            #define Z(vec, base)                                             \
                { if ((base + 0) >= lo && (base + 0) < hi) vec.x = 0.0f;     \
                  if ((base + 1) >= lo && (base + 1) < hi) vec.y = 0.0f;     \
                  if ((base + 2) >= lo && (base + 2) < hi) vec.z = 0.0f;     \
                  if ((base + 3) >= lo && (base + 3) < hi) vec.w = 0.0f; }
            Z(v0, 0) Z(v1, 4) Z(v2, 8) Z(v3, 12)
            #undef Z
        }
    }

    __builtin_nontemporal_store(v0, dst + i4 + 0);
    __builtin_nontemporal_store(v1, dst + i4 + 1);
    __builtin_nontemporal_store(v2, dst + i4 + 2);
    __builtin_nontemporal_store(v3, dst + i4 + 3);
}

extern "C" void kernel_launch(void* const* d_in, const int* in_sizes, int n_in,
                              void* d_out, int out_size, void* d_ws, size_t ws_size,
                              hipStream_t stream) {
    const vf4* img  = (const vf4*)d_in[0];
    const int* yidx = (const int*)d_in[1];
    const int* xidx = (const int*)d_in[2];

    int total16 = out_size / 16;                 // 2,408,448 chunks
    int blocks  = total16 / 256;                 // 9408, exact
    rsd_kernel<<<blocks, 256, 0, stream>>>(img, yidx, xidx, (vf4*)d_out);
}

// Round 5
// 266.557 us; speedup vs baseline: 1.1733x; 1.1733x over previous
//
#include <hip/hip_runtime.h>

// img: [B=256, C=3, H=224, W=224] fp32; y_idx/x_idx: [B] int32; 32x32 square
// zeroed per batch across all channels.
//
// R4 lesson (counters): per-thread 64B chunks -> 16B/lane @ 64B stride per
// store instruction -> partial-line HBM writes, WRITE_SIZE inflated 1.55x,
// 2.8 TB/s. Fix: LANE-CONTIGUOUS float4 (64 lanes x 16B = 1KB/instr), 4
// float4s per thread at stride 256 for pipelining.
// Loads: plain (harness restore leaves input L3-hot; FETCH was only 80MB).
// Stores: nontemporal (zero reuse; full lines now, so no partial-line RMW).

#define SQ 32
#define B_ 256
#define C_ 3
#define H_ 224
#define W_ 224
#define W4 (W_ / 4)        // 56 float4s per row; float4 never crosses a row
#define ROWS_PER_B (C_ * H_)

typedef float vf4 __attribute__((ext_vector_type(4)));

__global__ __launch_bounds__(256) void rsd_kernel(const vf4* __restrict__ src,
                                                  const int* __restrict__ y_idx,
                                                  const int* __restrict__ x_idx,
                                                  vf4* __restrict__ dst) {
    int base = blockIdx.x * 1024 + threadIdx.x;   // 4 float4s per thread
#pragma unroll
    for (int k = 0; k < 4; ++k) {
        int i4 = base + k * 256;

        vf4 v = src[i4];                          // plain cached load (L3-hot)

        // decode: row t = i4/56, w0 = (i4%56)*4; h = t%224; b = t/(3*224)
        int t  = i4 / W4;
        int w0 = (i4 - t * W4) << 2;
        int bc = t / H_;
        int h  = t - bc * H_;
        int b  = bc / C_;

        int y0 = y_idx[b];
        int x0 = x_idx[b];

        if (h >= y0 && h < y0 + SQ) {
            if ((w0 + 0) >= x0 && (w0 + 0) < x0 + SQ) v.x = 0.0f;
            if ((w0 + 1) >= x0 && (w0 + 1) < x0 + SQ) v.y = 0.0f;
            if ((w0 + 2) >= x0 && (w0 + 2) < x0 + SQ) v.z = 0.0f;
            if ((w0 + 3) >= x0 && (w0 + 3) < x0 + SQ) v.w = 0.0f;
        }

        __builtin_nontemporal_store(v, dst + i4);
    }
}

extern "C" void kernel_launch(void* const* d_in, const int* in_sizes, int n_in,
                              void* d_out, int out_size, void* d_ws, size_t ws_size,
                              hipStream_t stream) {
    const vf4* img  = (const vf4*)d_in[0];
    const int* yidx = (const int*)d_in[1];
    const int* xidx = (const int*)d_in[2];

    int total4 = out_size / 4;        // 9,633,792 float4s
    int blocks = total4 / 1024;       // 9408, exact (256*3*224*224 % 4096 == 0)
    rsd_kernel<<<blocks, 256, 0, stream>>>(img, yidx, xidx, (vf4*)d_out);
}

// Round 6
// 264.234 us; speedup vs baseline: 1.1836x; 1.0088x over previous
//
#include <hip/hip_runtime.h>

// img: [B=256, C=3, H=224, W=224] fp32; y_idx/x_idx: [B] int32; 32x32 square
// zeroed per batch across all channels.
//
// R5 lesson: every hand-rolled CU read+write stream lands at ~2.5-3 TB/s HBM
// while the runtime's fillBuffer hits 6.66 TB/s. Experiment: let the runtime
// do the bulk move (hipMemcpyAsync d2d -> tuned blit/SDMA path, graph-safe
// per harness contract), then zero the 256*3*32*32*4B = 3.1 MB of squares
// with a tiny kernel. rocprof will name the blit dispatch + its BW, settling
// whether ~3 TB/s is a CU-kernel artifact or the environment ceiling.

#define SQ 32
#define B_ 256
#define C_ 3
#define H_ 224
#define W_ 224
#define IMG_ELEMS (C_ * H_ * W_)   // 150528 floats per batch

// One block per batch. 3*32*32 = 3072 floats; 12 per thread.
// Row segments are 128B contiguous (32 floats); x0 is not 4-aligned so use
// scalar dword stores: each half-wave (32 lanes) covers one row segment.
__global__ __launch_bounds__(256) void zero_kernel(const int* __restrict__ y_idx,
                                                   const int* __restrict__ x_idx,
                                                   float* __restrict__ out) {
    int b  = blockIdx.x;
    int y0 = y_idx[b];
    int x0 = x_idx[b];
    float* img = out + (size_t)b * IMG_ELEMS;
#pragma unroll
    for (int t = 0; t < 12; ++t) {            // 3072 / 256 = 12
        int idx = t * 256 + threadIdx.x;
        int c   = idx >> 10;                  // /1024
        int dy  = (idx >> 5) & 31;            // (/32)%32
        int dx  = idx & 31;                   // %32
        img[(c * H_ + y0 + dy) * W_ + x0 + dx] = 0.0f;
    }
}

extern "C" void kernel_launch(void* const* d_in, const int* in_sizes, int n_in,
                              void* d_out, int out_size, void* d_ws, size_t ws_size,
                              hipStream_t stream) {
    const float* img  = (const float*)d_in[0];
    const int*   yidx = (const int*)d_in[1];
    const int*   xidx = (const int*)d_in[2];

    size_t nbytes = (size_t)out_size * sizeof(float);   // 154,140,672 B
    hipMemcpyAsync(d_out, img, nbytes, hipMemcpyDeviceToDevice, stream);
    zero_kernel<<<B_, 256, 0, stream>>>(yidx, xidx, (float*)d_out);
}